// Round 6
// baseline (2966.173 us; speedup 1.0000x reference)
//
#include <hip/hip_runtime.h>
#include <math.h>

#define FRAME 128
#define HOPW 64
#define SLEN 65536
#define IRLEN 1024
#define NFB 1006          // feedback iterations
#define RMASK 2047
#define PI_D 3.14159265358979323846

__device__ __forceinline__ float clip1(float v) { return fminf(1.0f, fmaxf(-1.0f, v)); }

// Raw barrier: drains LDS ops only; global loads/stores stay in flight.
__device__ __forceinline__ void loop_barrier() {
    __builtin_amdgcn_sched_barrier(0);
    asm volatile("s_waitcnt lgkmcnt(0)" ::: "memory");
    __builtin_amdgcn_s_barrier();
    __builtin_amdgcn_sched_barrier(0);
}

// Roles (768 threads = 12 waves):
//  tid [0,128)   waves 0-1 : w-recurrence (head sums + ring head write + OLA out)
//  tid [128,640) waves 2-9 : head partials (pre-A) + tail partials (post-A)
//                            kg=(tid-128)>>7 wave-uniform, 8 tail outputs/thread
//  tid [640,768) waves 10-11: bulk ring apply of conv_{i-1} p in [192,1152) + x commit
__global__ __launch_bounds__(768) void howl_fused(const float* __restrict__ x,
                                                  const float* __restrict__ ir,
                                                  float* __restrict__ out) {
    __shared__ __align__(16) float ring[2048];
    __shared__ __align__(16) float part[2][4][1152];  // [buf][kg][p]
    __shared__ float irl[IRLEN];
    __shared__ float wlds[FRAME];
    __shared__ float red1[1024];
    __shared__ float red2[1024];
    __shared__ float invfs;

    const int tid = threadIdx.x;
    const int lane = tid & 63;

    // ---- prologue: stage IR + raw x window ----
    for (int idx = tid; idx < IRLEN; idx += 768) irl[idx] = ir[idx];
    for (int idx = tid; idx < 1216; idx += 768) ring[idx] = x[idx];  // raw
    if (tid >= 513) { red1[tid] = -INFINITY; red2[tid] = 0.f; }
    if (tid < 256) { red1[768 + tid] = -INFINITY; red2[768 + tid] = 0.f; }
    __syncthreads();

    // ---- DFT power spectrum (4-way ILP recurrence, double precision) ----
    if (tid < 513) {
        double th = -2.0 * PI_D * (double)tid / 1024.0;
        double c4 = cos(4.0 * th), s4 = sin(4.0 * th);
        double wr0 = 1.0,           wi0 = 0.0;
        double wr1 = cos(th),       wi1 = sin(th);
        double wr2 = cos(2.0 * th), wi2 = sin(2.0 * th);
        double wr3 = cos(3.0 * th), wi3 = sin(3.0 * th);
        double ar0 = 0, ai0 = 0, ar1 = 0, ai1 = 0, ar2 = 0, ai2 = 0, ar3 = 0, ai3 = 0;
        for (int m = 0; m < 256; ++m) {
            double x0 = irl[4 * m], x1 = irl[4 * m + 1], x2 = irl[4 * m + 2], x3 = irl[4 * m + 3];
            ar0 += x0 * wr0; ai0 += x0 * wi0;
            ar1 += x1 * wr1; ai1 += x1 * wi1;
            ar2 += x2 * wr2; ai2 += x2 * wi2;
            ar3 += x3 * wr3; ai3 += x3 * wi3;
            double t;
            t = wr0 * c4 - wi0 * s4; wi0 = wr0 * s4 + wi0 * c4; wr0 = t;
            t = wr1 * c4 - wi1 * s4; wi1 = wr1 * s4 + wi1 * c4; wr1 = t;
            t = wr2 * c4 - wi2 * s4; wi2 = wr2 * s4 + wi2 * c4; wr2 = t;
            t = wr3 * c4 - wi3 * s4; wi3 = wr3 * s4 + wi3 * c4; wr3 = t;
        }
        double re = (ar0 + ar1) + (ar2 + ar3);
        double im = (ai0 + ai1) + (ai2 + ai3);
        float mag = (float)sqrt(re * re + im * im);
        float pw = mag * mag;
        double ph = atan2(im, re);
        int ok = (ph > -0.1 && ph < 0.1) ? 1 : 0;
        red1[tid] = ok ? pw : -INFINITY;
        red2[tid] = pw;
    }
    __syncthreads();
    for (int st = 512; st > 0; st >>= 1) {
        if (tid < st) {
            red1[tid] = fmaxf(red1[tid], red1[tid + st]);
            red2[tid] = red2[tid] + red2[tid + st];
        }
        __syncthreads();
    }
    if (tid == 0) {
        float peak = red1[0];
        float MLG = red2[0] / 513.0f;
        float MSG = -10.0f * log10f(peak / MLG);
        float target_gain = MSG + 2.0f;
        float mean_gain = 10.0f * log10f(MLG);
        invfs = powf(0.5f, (target_gain - mean_gain) / 6.0f);
    }
    __syncthreads();
    const float fbc = invfs;

    // ---- per-role setup ----
    float hvs = 0.f, tl = 0.f, xv = 0.f;
    float wirH[32];   // head-partial ir window (tail-wave threads)
    float wirT[39];   // tail-partial ir window
    int kg32 = 0, pbase = 0, Ptail = 0;

    if (tid < FRAME) {
        hvs = (float)(0.5 * (1.0 - cos(PI_D * (double)tid / 64.0)));
        wlds[tid] = hvs * ring[tid];               // w_0 from raw x
        if (tid < HOPW) out[tid] = clip1(wlds[tid]);  // OLA block 0
    }
    if (tid >= 128 && tid < 640) {
        int idx = tid - 128;
        int kg = idx >> 7;
        int obh = idx & 127;
        kg32 = kg * 32;
        pbase = kg * 1152;
        Ptail = 128 + obh * 8;
#pragma unroll
        for (int j = 0; j < 32; ++j) {
            int id = obh - kg32 - 31 + j;
            wirH[j] = (id >= 0) ? irl[id] / fbc : 0.f;
        }
#pragma unroll
        for (int m = 0; m < 39; ++m) {
            int id = Ptail - kg32 - 31 + m;      // always >= 1
            wirT[m] = (id < IRLEN) ? irl[id] / fbc : 0.f;
        }
    }
    if (tid >= 704) xv = x[1216 + (tid - 704)];    // prefetch for iter-0 commit
    __syncthreads();

#pragma unroll 1
    for (int i = 0; i < NFB; ++i) {
        const int base = i * HOPW;
        float* cur = &part[i & 1][0][0];
        float* prev = &part[(i + 1) & 1][0][0];

        float ts[32];
        // ---- TOP (pre-A): head partials on tail waves; tl snapshot on wave 0 ----
        if (tid >= 128 && tid < 640) {
            float wreg = wlds[kg32 + (lane & 31)];
#pragma unroll
            for (int kk = 0; kk < 32; ++kk)
                ts[kk] = __int_as_float(__builtin_amdgcn_readlane(__float_as_int(wreg), 31 - kk));
            float ah = 0.f;
#pragma unroll
            for (int kk = 0; kk < 32; ++kk) ah = fmaf(ts[kk], wirH[kk], ah);
            int obh = (tid - 128) & 127;
            cur[pbase + obh] = ah;
        } else if (tid < 64) {
            tl = wlds[64 + lane];                  // w_i[64:128] for OLA
        }
        loop_barrier();

        // ---- phase 2/3 (concurrent, disjoint ring ranges) ----
        if (tid < 128) {
            // w-recurrence: slots [base+64, base+192)
            int s = tid;
            int slot = (base + 64 + s) & RMASK;
            float rr = ring[slot];
            float sc4 = ((cur[s] + cur[1152 + s]) + cur[2304 + s]) + cur[3456 + s];
            float v;
            if (s >= 64 && i > 0) {                // conv_{i-1} tail-slice [128,192)
                int t = 64 + s;
                float pm = ((prev[t] + prev[1152 + t]) + prev[2304 + t]) + prev[3456 + t];
                v = clip1(clip1(rr + pm) + sc4);
            } else {
                v = clip1(rr + sc4);
            }
            ring[slot] = v;
            float wn = hvs * v;
            wlds[s] = wn;                          // w_{i+1}
            if (s < 64) out[base + 64 + s] = clip1(wn + tl);   // OLA block i+1
        } else if (tid < 640) {
            // tail partials: outputs [Ptail, Ptail+8)
            float a0 = 0, a1 = 0, a2 = 0, a3 = 0, a4 = 0, a5 = 0, a6 = 0, a7 = 0;
#pragma unroll
            for (int kk = 0; kk < 32; ++kk) {
                float sc = ts[kk];
                a0 = fmaf(sc, wirT[kk + 0], a0);
                a1 = fmaf(sc, wirT[kk + 1], a1);
                a2 = fmaf(sc, wirT[kk + 2], a2);
                a3 = fmaf(sc, wirT[kk + 3], a3);
                a4 = fmaf(sc, wirT[kk + 4], a4);
                a5 = fmaf(sc, wirT[kk + 5], a5);
                a6 = fmaf(sc, wirT[kk + 6], a6);
                a7 = fmaf(sc, wirT[kk + 7], a7);
            }
            float* pw = cur + pbase + Ptail;
            *(float4*)(pw + 0) = make_float4(a0, a1, a2, a3);
            *(float4*)(pw + 4) = make_float4(a4, a5, a6, a7);
        } else {
            // bulk apply of conv_{i-1}: p in [192,1152) -> slots [base+192, base+1152)
            int a = tid - 640;
            if (i > 0) {
#pragma unroll
                for (int r = 0; r < 2; ++r) {
                    int q = a + r * 128;
                    if (q < 240) {
                        int p = 192 + 4 * q;
                        float4 g0 = *(const float4*)&prev[p];
                        float4 g1 = *(const float4*)&prev[1152 + p];
                        float4 g2 = *(const float4*)&prev[2304 + p];
                        float4 g3 = *(const float4*)&prev[3456 + p];
                        int slot = (base + p) & RMASK;
                        float4 rv = *(float4*)&ring[slot];
                        rv.x = clip1(rv.x + (((g0.x + g1.x) + g2.x) + g3.x));
                        rv.y = clip1(rv.y + (((g0.y + g1.y) + g2.y) + g3.y));
                        rv.z = clip1(rv.z + (((g0.z + g1.z) + g2.z) + g3.z));
                        rv.w = clip1(rv.w + (((g0.w + g1.w) + g2.w) + g3.w));
                        *(float4*)&ring[slot] = rv;
                    }
                }
            }
            if (tid >= 704) {                      // wave 11: x commit + prefetch
                int l = tid - 704;
                int pos = base + 1216 + l;
                if (pos < SLEN) ring[pos & RMASK] = clip1(xv);
                int np = pos + HOPW;
                xv = (np < SLEN) ? x[np] : 0.f;
            }
        }
        loop_barrier();
    }

    __syncthreads();
    // ---- epilogue: final OLA block + zero tail ----
    if (tid < 64) out[64448 + tid] = clip1(wlds[64 + tid]);   // w_1006[64:128]
    for (int idx = 64512 + tid; idx < SLEN; idx += 768) out[idx] = 0.f;
}

extern "C" void kernel_launch(void* const* d_in, const int* in_sizes, int n_in,
                              void* d_out, int out_size, void* d_ws, size_t ws_size,
                              hipStream_t stream) {
    const float* x = (const float*)d_in[0];
    const float* ir = (const float*)d_in[1];
    float* out = (float*)d_out;
    (void)d_ws; (void)ws_size; (void)in_sizes; (void)n_in; (void)out_size;

    hipLaunchKernelGGL(howl_fused, dim3(1), dim3(768), 0, stream, x, ir, out);
}

// Round 7
// 1020.277 us; speedup vs baseline: 2.9072x; 2.9072x over previous
//
#include <hip/hip_runtime.h>
#include <math.h>

#define FRAME 128
#define HOPW 64
#define SLEN 65536
#define IRLEN 1024
#define NFB 1006          // feedback iterations
#define RMASK 2047
#define PI_D 3.14159265358979323846

__device__ __forceinline__ float clip1(float v) { return fminf(1.0f, fmaxf(-1.0f, v)); }

// Raw barrier: drains LDS ops only; global loads/stores stay in flight.
__device__ __forceinline__ void loop_barrier() {
    __builtin_amdgcn_sched_barrier(0);
    asm volatile("s_waitcnt lgkmcnt(0)" ::: "memory");
    __builtin_amdgcn_s_barrier();
    __builtin_amdgcn_sched_barrier(0);
}

// Round-2 structure + same-iteration tail-apply in the post phase.
// 768 threads = 12 waves. kg = tid/192 (wave-uniform 32-tap group), ob = tid%192
// -> 6 conv outputs/thread, constant 37-float IR window in VGPRs.
// Phase B: pure FMA partials (+OLA on wave 0, x-commit on wave 11).
// Post:    head finalize (waves 0-1: conv_i p in [0,128) -> ring + w_{i+1})
//          concurrent with tail-apply (waves 2-5: conv_i p in [128,1152), float4).
__global__ __launch_bounds__(768) void howl_fused(const float* __restrict__ x,
                                                  const float* __restrict__ ir,
                                                  float* __restrict__ out) {
    __shared__ __align__(16) float ring[2048];
    __shared__ __align__(16) float part[4][1152];   // single-buffered partials
    __shared__ float irl[IRLEN];
    __shared__ float wlds[FRAME];
    __shared__ float red1[1024];
    __shared__ float red2[1024];
    __shared__ float invfs;

    const int tid = threadIdx.x;
    const int lane = tid & 63;
    const int wvid = tid >> 6;
    const int kg = tid / 192;
    const int ob = tid % 192;
    const int q = ob * 6;
    const int lo = q - kg * 32 - 31;

    // ---- prologue: stage IR + raw x window ----
    for (int idx = tid; idx < IRLEN; idx += 768) irl[idx] = ir[idx];
    for (int idx = tid; idx < 1216; idx += 768) ring[idx] = x[idx];  // raw
    if (tid >= 513) { red1[tid] = -INFINITY; red2[tid] = 0.f; }
    if (tid < 256) { red1[768 + tid] = -INFINITY; red2[768 + tid] = 0.f; }
    __syncthreads();

    // ---- DFT power spectrum (4-way ILP recurrence, double precision) ----
    if (tid < 513) {
        double th = -2.0 * PI_D * (double)tid / 1024.0;
        double c4 = cos(4.0 * th), s4 = sin(4.0 * th);
        double wr0 = 1.0,           wi0 = 0.0;
        double wr1 = cos(th),       wi1 = sin(th);
        double wr2 = cos(2.0 * th), wi2 = sin(2.0 * th);
        double wr3 = cos(3.0 * th), wi3 = sin(3.0 * th);
        double ar0 = 0, ai0 = 0, ar1 = 0, ai1 = 0, ar2 = 0, ai2 = 0, ar3 = 0, ai3 = 0;
        for (int m = 0; m < 256; ++m) {
            double x0 = irl[4 * m], x1 = irl[4 * m + 1], x2 = irl[4 * m + 2], x3 = irl[4 * m + 3];
            ar0 += x0 * wr0; ai0 += x0 * wi0;
            ar1 += x1 * wr1; ai1 += x1 * wi1;
            ar2 += x2 * wr2; ai2 += x2 * wi2;
            ar3 += x3 * wr3; ai3 += x3 * wi3;
            double t;
            t = wr0 * c4 - wi0 * s4; wi0 = wr0 * s4 + wi0 * c4; wr0 = t;
            t = wr1 * c4 - wi1 * s4; wi1 = wr1 * s4 + wi1 * c4; wr1 = t;
            t = wr2 * c4 - wi2 * s4; wi2 = wr2 * s4 + wi2 * c4; wr2 = t;
            t = wr3 * c4 - wi3 * s4; wi3 = wr3 * s4 + wi3 * c4; wr3 = t;
        }
        double re = (ar0 + ar1) + (ar2 + ar3);
        double im = (ai0 + ai1) + (ai2 + ai3);
        float mag = (float)sqrt(re * re + im * im);
        float pw = mag * mag;
        double ph = atan2(im, re);
        int ok = (ph > -0.1 && ph < 0.1) ? 1 : 0;
        red1[tid] = ok ? pw : -INFINITY;
        red2[tid] = pw;
    }
    __syncthreads();
    for (int st = 512; st > 0; st >>= 1) {
        if (tid < st) {
            red1[tid] = fmaxf(red1[tid], red1[tid + st]);
            red2[tid] = red2[tid] + red2[tid + st];
        }
        __syncthreads();
    }
    if (tid == 0) {
        float peak = red1[0];
        float MLG = red2[0] / 513.0f;
        float MSG = -10.0f * log10f(peak / MLG);
        float target_gain = MSG + 2.0f;
        float mean_gain = 10.0f * log10f(MLG);
        invfs = powf(0.5f, (target_gain - mean_gain) / 6.0f);
    }
    __syncthreads();
    const float fbc = invfs;

    float wir[37];
#pragma unroll
    for (int j = 0; j < 37; ++j) {
        int idx = lo + j;
        wir[j] = (idx >= 0 && idx < IRLEN) ? irl[idx] / fbc : 0.f;
    }

    // head-finalize hann value (tid<128 only uses it)
    const float hvs = (float)(0.5 * (1.0 - cos(PI_D * (double)(tid & 127) / 64.0)));

    float tl = 0.f, xv = 0.f;
    if (tid < FRAME) wlds[tid] = hvs * ring[tid];   // w_0 from raw x
    if (wvid == 11) xv = x[1216 + lane];            // prefetch for iter-0 commit
    if (wvid < 2) __builtin_amdgcn_s_setprio(1);    // recurrence-closing crew
    __syncthreads();

#pragma unroll 1
    for (int i = 0; i < NFB; ++i) {
        const int base = i * HOPW;

        // ---- phase B: pure FMA partials (+OLA, x-commit) ----
        if (wvid == 0) {
            float w0v = wlds[lane];
            float w1v = wlds[64 + lane];
            out[base + lane] = clip1(w0v + tl);     // OLA output block i
            tl = w1v;
        } else if (wvid == 11) {
            int pos = base + 1216 + lane;
            if (pos < SLEN) ring[pos & RMASK] = clip1(xv);
            int np = pos + HOPW;
            xv = (np < SLEN) ? x[np] : 0.f;         // stays in flight across barriers
        }

        float wreg = wlds[kg * 32 + (lane & 31)];
        float a0 = 0, a1 = 0, a2 = 0, a3 = 0, a4 = 0, a5 = 0;
#pragma unroll
        for (int kk = 0; kk < 32; ++kk) {
            float sc = __int_as_float(__builtin_amdgcn_readlane(__float_as_int(wreg), 31 - kk));
            a0 = fmaf(sc, wir[kk + 0], a0);
            a1 = fmaf(sc, wir[kk + 1], a1);
            a2 = fmaf(sc, wir[kk + 2], a2);
            a3 = fmaf(sc, wir[kk + 3], a3);
            a4 = fmaf(sc, wir[kk + 4], a4);
            a5 = fmaf(sc, wir[kk + 5], a5);
        }
        float* pw = &part[kg][q];
        *(float2*)(pw + 0) = make_float2(a0, a1);
        *(float2*)(pw + 2) = make_float2(a2, a3);
        *(float2*)(pw + 4) = make_float2(a4, a5);

        loop_barrier();

        // ---- post: head finalize || tail-apply (same conv_i, disjoint slots) ----
        if (tid < 128) {
            // conv_i p in [0,128): ring RMW + w_{i+1}
            int s = tid;
            int slot = (base + 64 + s) & RMASK;
            float rr = ring[slot];
            float sc4 = ((part[0][s] + part[1][s]) + part[2][s]) + part[3][s];
            float v = clip1(rr + sc4);
            ring[slot] = v;
            wlds[s] = hvs * v;
        } else if (tid < 384) {
            // conv_i p in [128,1152): float4 RMW at slots [base+192, base+1216)
            int p = 128 + 4 * (tid - 128);
            float4 g0 = *(const float4*)&part[0][p];
            float4 g1 = *(const float4*)&part[1][p];
            float4 g2 = *(const float4*)&part[2][p];
            float4 g3 = *(const float4*)&part[3][p];
            int slot = (base + 64 + p) & RMASK;      // p%4==0 -> no wrap inside float4
            float4 rv = *(float4*)&ring[slot];
            rv.x = clip1(rv.x + (((g0.x + g1.x) + g2.x) + g3.x));
            rv.y = clip1(rv.y + (((g0.y + g1.y) + g2.y) + g3.y));
            rv.z = clip1(rv.z + (((g0.z + g1.z) + g2.z) + g3.z));
            rv.w = clip1(rv.w + (((g0.w + g1.w) + g2.w) + g3.w));
            *(float4*)&ring[slot] = rv;
        }

        loop_barrier();
    }

    // ---- epilogue: last frame's OLA blocks + zero tail ----
    if (wvid == 0) {
        out[64384 + lane] = clip1(wlds[lane] + tl);   // block 1006
        out[64448 + lane] = clip1(wlds[64 + lane]);   // block 1007
    }
    for (int idx = 64512 + tid; idx < SLEN; idx += 768) out[idx] = 0.f;
}

extern "C" void kernel_launch(void* const* d_in, const int* in_sizes, int n_in,
                              void* d_out, int out_size, void* d_ws, size_t ws_size,
                              hipStream_t stream) {
    const float* x = (const float*)d_in[0];
    const float* ir = (const float*)d_in[1];
    float* out = (float*)d_out;
    (void)d_ws; (void)ws_size; (void)in_sizes; (void)n_in; (void)out_size;

    hipLaunchKernelGGL(howl_fused, dim3(1), dim3(768), 0, stream, x, ir, out);
}